// Round 2
// baseline (481.069 us; speedup 1.0000x reference)
//
#include <hip/hip_runtime.h>

#define HW    4096
#define CKD   64
#define CVD   512
#define NBATCH 8
#define BQ    64       // q per block
#define BM    64
#define NIT   64       // HW / BM
#define PSTR  72       // P-tile LDS row stride (bf16 elems): 144 B rows, 16B-aligned

typedef __attribute__((ext_vector_type(8))) short  short8;
typedef __attribute__((ext_vector_type(4))) float  floatx4;
typedef __attribute__((ext_vector_type(4))) int    intx4;
typedef __attribute__((ext_vector_type(2))) int    intx2;
typedef __attribute__((ext_vector_type(2))) float  floatx2;

static __device__ __forceinline__ unsigned short f2bf(float f) {
  unsigned u = __float_as_uint(f);
  u = (u + 0x7fffu + ((u >> 16) & 1u)) >> 16;   // RTNE
  return (unsigned short)u;
}
static __device__ __forceinline__ unsigned pack2(float a, float b) {
  return (unsigned)f2bf(a) | ((unsigned)f2bf(b) << 16);
}

// ---------------- merged pre-pass ----------------
// bx <128: Mk transpose+convert; 128..255: Qk; >=256: Mv pairwise convert.
// Transpose: thread owns one m-row: coalesced f32 column reads, writes one
// contiguous 128 B bf16 row [HW][CK].
__global__ __launch_bounds__(256) void prepass(
    const float* __restrict__ Mk, const float* __restrict__ Qk,
    const float* __restrict__ Mv,
    unsigned short* __restrict__ mkw, unsigned short* __restrict__ qkw,
    unsigned short* __restrict__ mvw)
{
  const int bx = blockIdx.x;
  if (bx < 256) {
    const float* src = (bx < 128) ? Mk : Qk;
    unsigned short* dstp = (bx < 128) ? mkw : qkw;
    const int bb = (bx & 127) >> 4;                       // batch
    const int m  = ((bx & 15) << 8) | threadIdx.x;
    const float* s = src + (size_t)bb * CKD * HW + m;
    intx4* d = (intx4*)(dstp + ((size_t)bb * HW + m) * CKD);
    #pragma unroll
    for (int v = 0; v < 8; ++v) {
      intx4 o;
      #pragma unroll
      for (int k = 0; k < 4; ++k) {
        float f0 = s[(size_t)(v * 8 + 2 * k    ) * HW];
        float f1 = s[(size_t)(v * 8 + 2 * k + 1) * HW];
        o[k] = (int)pack2(f0, f1);
      }
      d[v] = o;
    }
  } else {
    // mv: 8 f32 -> 8 bf16 per thread (32 B read, 16 B write)
    const size_t i = (size_t)(bx - 256) * 256 + threadIdx.x;
    const floatx4* s = (const floatx4*)Mv + i * 2;
    floatx4 f0 = s[0], f1 = s[1];
    intx4 o;
    o[0] = (int)pack2(f0.x, f0.y);
    o[1] = (int)pack2(f0.z, f0.w);
    o[2] = (int)pack2(f1.x, f1.y);
    o[3] = (int)pack2(f1.z, f1.w);
    ((intx4*)mvw)[i] = o;
  }
}

// fragment loaders, templated on storage dtype (BF=true: bf16 in ws)
template<bool BF>
static __device__ __forceinline__ short8 ld8_strided(const char* p, int idx) {
  short8 f;
  if constexpr (BF) {
    const unsigned short* q = (const unsigned short*)p + idx;
    #pragma unroll
    for (int j = 0; j < 8; ++j) f[j] = (short)q[(size_t)j * HW];
  } else {
    const float* q = (const float*)p + idx;
    #pragma unroll
    for (int j = 0; j < 8; ++j) f[j] = (short)f2bf(q[(size_t)j * HW]);
  }
  return f;
}
template<bool BF>
static __device__ __forceinline__ short8 ld8_contig(const char* p, size_t idx) {
  if constexpr (BF) {
    union { intx4 i; short8 s; } u;
    u.i = *(const intx4*)((const unsigned short*)p + idx);
    return u.s;
  } else {
    const float* q = (const float*)p + idx;
    short8 f;
    #pragma unroll
    for (int j = 0; j < 4; ++j) {
      unsigned v = pack2(q[2*j], q[2*j+1]);
      f[2*j]   = (short)(v & 0xffffu);
      f[2*j+1] = (short)(v >> 16);
    }
    return f;
  }
}

// BF=true:  mk = mkT [HW][CK] bf16, qk = qkT [HW][CK] bf16, mv = [CV][HW] bf16
// BF=false: original f32 layouts ([CK][HW], [CK][HW], [CV][HW])
// Block: 256 threads (4 waves), owns BQ=64 q-cols x all 512 cv rows.
// Wave w: GEMM1 for q-tile w (16 q); GEMM2 for cv rows [w*128, w*128+128).
// 2 blocks/CU -> independent barriers overlap GEMM1/exp with GEMM2 MFMA.
template<bool BF>
__global__ __launch_bounds__(256, 2) void attn_main(
    const void* __restrict__ Mkp, const void* __restrict__ Qkp,
    const void* __restrict__ Mvp, float* __restrict__ Out)
{
  __shared__ alignas(16) short Pt[2][BQ * PSTR];   // 18432 B
  __shared__ float lsum[BQ];

  const int bx   = blockIdx.x;
  const int b    = bx & 7;            // XCD-affine: batch b -> XCD b
  const int q0   = (bx >> 3) * BQ;
  const int tid  = threadIdx.x;
  const int w    = tid >> 6;          // wave 0..3
  const int lane = tid & 63;
  const int quad = lane >> 4;
  const int col  = lane & 15;

  const size_t esz = BF ? 2 : 4;
  const char* mk = (const char*)Mkp + (size_t)b * CKD * HW * esz;
  const char* qk = (const char*)Qkp + (size_t)b * CKD * HW * esz;
  const char* mv = (const char*)Mvp + (size_t)b * CVD * HW * esz;
  float*      out = Out + (size_t)b * CVD * HW;

  if (tid < BQ) lsum[tid] = 0.0f;

  // B-fragments of qk (fixed for whole block): wave w owns q-tile w.
  short8 bq[2];
  #pragma unroll
  for (int ks = 0; ks < 2; ++ks) {
    if constexpr (BF)
      bq[ks] = ld8_contig<true>(qk, (size_t)(q0 + w*16 + col) * CKD + ks*32 + quad*8);
    else
      bq[ks] = ld8_strided<false>(qk, (ks*32 + quad*8) * HW + q0 + w*16 + col);
  }

  floatx4 acc[8][4];   // [ch][qh]: wave w owns cv rows [w*128, +128), all 64 q
  #pragma unroll
  for (int i = 0; i < 8; ++i)
    #pragma unroll
    for (int j = 0; j < 4; ++j) acc[i][j] = (floatx4)0.0f;

  float lacc = 0.0f;
  const float SC = 0.18033688011112042f;   // (1/sqrt(64)) * log2(e)

  __syncthreads();

  for (int it = 0; it < NIT; ++it) {
    const int m0 = it * BM;
    short* Pb = &Pt[it & 1][0];

    // ---- prefetch mv fragments for GEMM2 first half (ch 0..3): latency
    //      hides under GEMM1 (consumed only after the barrier)
    short8 avA[4][2];
    #pragma unroll
    for (int ch = 0; ch < 4; ++ch)
      #pragma unroll
      for (int ks = 0; ks < 2; ++ks)
        avA[ch][ks] = ld8_contig<BF>(mv, (size_t)(w*128 + ch*16 + col) * HW + m0 + ks*32 + quad*8);

    // ---- GEMM1: S[m][q], wave w does tiles (mh=0..3, q-tile w); exp -> P^T in LDS
    #pragma unroll
    for (int mh = 0; mh < 4; ++mh) {
      floatx4 s = (floatx4)0.0f;
      #pragma unroll
      for (int ks = 0; ks < 2; ++ks) {
        short8 a;
        if constexpr (BF)   // A[m=col][k=c] from mkT: one dwordx4, contiguous in c
          a = ld8_contig<true>(mk, (size_t)(m0 + mh*16 + col) * CKD + ks*32 + quad*8);
        else
          a = ld8_strided<false>(mk, (ks*32 + quad*8) * HW + m0 + mh*16 + col);
        s = __builtin_amdgcn_mfma_f32_16x16x32_bf16(a, bq[ks], s, 0, 0, 0);
      }
      // C layout: n=q=col, m = quad*4 + r
      const float p0 = exp2f(s[0] * SC);
      const float p1 = exp2f(s[1] * SC);
      const float p2 = exp2f(s[2] * SC);
      const float p3 = exp2f(s[3] * SC);
      lacc += (p0 + p1) + (p2 + p3);
      intx2 pv;
      pv[0] = (int)pack2(p0, p1);
      pv[1] = (int)pack2(p2, p3);
      *(intx2*)(Pb + (w*16 + col) * PSTR + mh*16 + quad*4) = pv;
    }
    __syncthreads();   // single barrier/iter; P double-buffered

    // ---- GEMM2: O[cv][q] += mv[cv][m] * P[m][q]
    // second-half mv loads issued first so latency hides under first-half MFMAs
    short8 avB[4][2];
    #pragma unroll
    for (int ch = 0; ch < 4; ++ch)
      #pragma unroll
      for (int ks = 0; ks < 2; ++ks)
        avB[ch][ks] = ld8_contig<BF>(mv, (size_t)(w*128 + 64 + ch*16 + col) * HW + m0 + ks*32 + quad*8);

    union { intx4 i; short8 s; } u[4][2];
    #pragma unroll
    for (int qh = 0; qh < 4; ++qh) {
      u[qh][0].i = *(const intx4*)(Pb + (qh*16 + col) * PSTR + quad*8);
      u[qh][1].i = *(const intx4*)(Pb + (qh*16 + col) * PSTR + 32 + quad*8);
    }

    __builtin_amdgcn_s_setprio(1);
    #pragma unroll
    for (int ch = 0; ch < 4; ++ch)
      #pragma unroll
      for (int qh = 0; qh < 4; ++qh) {
        acc[ch][qh] = __builtin_amdgcn_mfma_f32_16x16x32_bf16(avA[ch][0], u[qh][0].s, acc[ch][qh], 0, 0, 0);
        acc[ch][qh] = __builtin_amdgcn_mfma_f32_16x16x32_bf16(avA[ch][1], u[qh][1].s, acc[ch][qh], 0, 0, 0);
      }
    #pragma unroll
    for (int ch = 0; ch < 4; ++ch)
      #pragma unroll
      for (int qh = 0; qh < 4; ++qh) {
        acc[4+ch][qh] = __builtin_amdgcn_mfma_f32_16x16x32_bf16(avB[ch][0], u[qh][0].s, acc[4+ch][qh], 0, 0, 0);
        acc[4+ch][qh] = __builtin_amdgcn_mfma_f32_16x16x32_bf16(avB[ch][1], u[qh][1].s, acc[4+ch][qh], 0, 0, 0);
      }
    __builtin_amdgcn_s_setprio(0);
  }

  // ---- softmax denominators: 4 quads contribute per q column
  atomicAdd(&lsum[w*16 + col], lacc);
  __syncthreads();

  float rl[4];
  #pragma unroll
  for (int qh = 0; qh < 4; ++qh) rl[qh] = 1.0f / lsum[qh*16 + col];

  // ---- epilogue: normalize + store f32
  #pragma unroll
  for (int ch = 0; ch < 8; ++ch) {
    #pragma unroll
    for (int r = 0; r < 4; ++r) {
      const int cv = w*128 + ch*16 + quad*4 + r;
      float* orow = out + (size_t)cv * HW + q0 + col;
      #pragma unroll
      for (int qh = 0; qh < 4; ++qh)
        orow[qh*16] = acc[ch][qh][r] * rl[qh];
    }
  }
}

extern "C" void kernel_launch(void* const* d_in, const int* in_sizes, int n_in,
                              void* d_out, int out_size, void* d_ws, size_t ws_size,
                              hipStream_t stream) {
  const float* Mk = (const float*)d_in[0];
  const float* Qk = (const float*)d_in[1];
  const float* Mv = (const float*)d_in[2];
  float* Out = (float*)d_out;
  (void)in_sizes; (void)n_in; (void)out_size;

  const size_t NMK = (size_t)NBATCH * CKD * HW;   // 2,097,152
  const size_t NMV = (size_t)NBATCH * CVD * HW;   // 16,777,216
  const size_t need = (2 * NMK + NMV) * 2;        // 41,943,040 B

  if (ws_size >= need) {
    unsigned short* mkw = (unsigned short*)d_ws;
    unsigned short* qkw = mkw + NMK;
    unsigned short* mvw = qkw + NMK;
    const int mvBlocks = (int)(NMV / (256 * 8));  // 8 elems/thread
    prepass<<<256 + mvBlocks, 256, 0, stream>>>(Mk, Qk, Mv, mkw, qkw, mvw);
    attn_main<true><<<NBATCH * (HW/BQ), 256, 0, stream>>>(mkw, qkw, mvw, Out);
  } else {
    attn_main<false><<<NBATCH * (HW/BQ), 256, 0, stream>>>(Mk, Qk, Mv, Out);
  }
}

// Round 4
// 418.449 us; speedup vs baseline: 1.1496x; 1.1496x over previous
//
#include <hip/hip_runtime.h>

#define HW    4096
#define CKD   64
#define CVD   512
#define NBATCH 8
#define BQ    128
#define BM    64
#define NIT   64       // HW / BM
#define PSTR  72       // P-tile LDS row stride (bf16 elems): 144 B rows, 16B-aligned

typedef __attribute__((ext_vector_type(8))) short  short8;
typedef __attribute__((ext_vector_type(4))) float  floatx4;
typedef __attribute__((ext_vector_type(4))) int    intx4;
typedef __attribute__((ext_vector_type(2))) int    intx2;
typedef __attribute__((ext_vector_type(2))) float  floatx2;

static __device__ __forceinline__ unsigned short f2bf(float f) {
  unsigned u = __float_as_uint(f);
  u = (u + 0x7fffu + ((u >> 16) & 1u)) >> 16;   // RTNE
  return (unsigned short)u;
}
static __device__ __forceinline__ unsigned pack2(float a, float b) {
  return (unsigned)f2bf(a) | ((unsigned)f2bf(b) << 16);
}

// ---------------- merged pre-pass ----------------
// bx <128: Mk transpose+convert; 128..255: Qk; >=256: Mv pairwise convert.
__global__ __launch_bounds__(256) void prepass(
    const float* __restrict__ Mk, const float* __restrict__ Qk,
    const float* __restrict__ Mv,
    unsigned short* __restrict__ mkw, unsigned short* __restrict__ qkw,
    unsigned short* __restrict__ mvw)
{
  const int bx = blockIdx.x;
  if (bx < 256) {
    const float* src = (bx < 128) ? Mk : Qk;
    unsigned short* dstp = (bx < 128) ? mkw : qkw;
    const int bb = (bx & 127) >> 4;                       // batch
    const int m  = ((bx & 15) << 8) | threadIdx.x;
    const float* s = src + (size_t)bb * CKD * HW + m;
    intx4* d = (intx4*)(dstp + ((size_t)bb * HW + m) * CKD);
    #pragma unroll
    for (int v = 0; v < 8; ++v) {
      intx4 o;
      #pragma unroll
      for (int k = 0; k < 4; ++k) {
        float f0 = s[(size_t)(v * 8 + 2 * k    ) * HW];
        float f1 = s[(size_t)(v * 8 + 2 * k + 1) * HW];
        o[k] = (int)pack2(f0, f1);
      }
      d[v] = o;
    }
  } else {
    const size_t i = (size_t)(bx - 256) * 256 + threadIdx.x;
    const floatx4* s = (const floatx4*)Mv + i * 2;
    floatx4 f0 = s[0], f1 = s[1];
    intx4 o;
    o[0] = (int)pack2(f0.x, f0.y);
    o[1] = (int)pack2(f0.z, f0.w);
    o[2] = (int)pack2(f1.x, f1.y);
    o[3] = (int)pack2(f1.z, f1.w);
    ((intx4*)mvw)[i] = o;
  }
}

// fragment loaders, templated on storage dtype (BF=true: bf16 in ws)
template<bool BF>
static __device__ __forceinline__ short8 ld8_strided(const char* p, int idx) {
  short8 f;
  if constexpr (BF) {
    const unsigned short* q = (const unsigned short*)p + idx;
    #pragma unroll
    for (int j = 0; j < 8; ++j) f[j] = (short)q[(size_t)j * HW];
  } else {
    const float* q = (const float*)p + idx;
    #pragma unroll
    for (int j = 0; j < 8; ++j) f[j] = (short)f2bf(q[(size_t)j * HW]);
  }
  return f;
}
template<bool BF>
static __device__ __forceinline__ short8 ld8_contig(const char* p, size_t idx) {
  if constexpr (BF) {
    union { intx4 i; short8 s; } u;
    u.i = *(const intx4*)((const unsigned short*)p + idx);
    return u.s;
  } else {
    const float* q = (const float*)p + idx;
    short8 f;
    #pragma unroll
    for (int j = 0; j < 4; ++j) {
      unsigned v = pack2(q[2*j], q[2*j+1]);
      f[2*j]   = (short)(v & 0xffffu);
      f[2*j+1] = (short)(v >> 16);
    }
    return f;
  }
}

// A-fragment of mk (BF: from mkT [HW][CK], one dwordx4)
template<bool BF>
static __device__ __forceinline__ short8 ldA(const char* mk, int m0, int mh,
                                             int ks, int quad, int col) {
  if constexpr (BF)
    return ld8_contig<true>(mk, (size_t)(m0 + mh*16 + col) * CKD + ks*32 + quad*8);
  else
    return ld8_strided<false>(mk, (ks*32 + quad*8) * HW + m0 + mh*16 + col);
}

#define MFMA16(a, b, c) __builtin_amdgcn_mfma_f32_16x16x32_bf16((a), (b), (c), 0, 0, 0)

// One pipelined step: GEMM2(it) using avCur + P-read-buffer Pr,
// interleaved with GEMM1(it+1) -> Pw, and mv/mk loads for it+1.
template<bool BF>
static __device__ __forceinline__ void attn_step(
    const char* mk, const char* mv,
    const short8 (&bq)[2], floatx4 (&acc)[4][8], float& lacc,
    int w, int quad, int col, int it,
    const short8 (&avCur)[4][2], short8 (&avNext)[4][2],
    const short* Pr, short* Pw)
{
  const float SC = 0.18033688011112042f;   // (1/sqrt(64)) * log2(e)
  const int itn = it + 1;
  const bool doG1 = (itn < NIT);
  const int m0n = (doG1 ? itn : (NIT - 1)) * BM;

  // A-fragments for GEMM1(it+1): consumed at qh>=4 (~40 MFMAs of latency cover)
  short8 aF[4][2];
  #pragma unroll
  for (int mh = 0; mh < 4; ++mh)
    #pragma unroll
    for (int ks = 0; ks < 2; ++ks)
      aF[mh][ks] = ldA<BF>(mk, m0n, mh, ks, quad, col);

  // mv fragments for GEMM2(it+1): consumed after the next barrier
  #pragma unroll
  for (int ch = 0; ch < 4; ++ch)
    #pragma unroll
    for (int ks = 0; ks < 2; ++ks)
      avNext[ch][ks] = ld8_contig<BF>(mv,
          (size_t)(w*64 + ch*16 + col) * HW + m0n + ks*32 + quad*8);

  #pragma unroll
  for (int qh = 0; qh < 8; ++qh) {
    union { intx4 i; short8 s; } u0, u1;
    u0.i = *(const intx4*)(Pr + (qh*16 + col) * PSTR + quad*8);
    u1.i = *(const intx4*)(Pr + (qh*16 + col) * PSTR + 32 + quad*8);
    #pragma unroll
    for (int ch = 0; ch < 4; ++ch) {
      acc[ch][qh] = MFMA16(avCur[ch][0], u0.s, acc[ch][qh]);
      acc[ch][qh] = MFMA16(avCur[ch][1], u1.s, acc[ch][qh]);
    }
    if (qh >= 4 && doG1) {
      const int mh = qh - 4;
      floatx4 s = (floatx4)0.0f;
      s = MFMA16(aF[mh][0], bq[0], s);
      s = MFMA16(aF[mh][1], bq[1], s);
      const float p0 = exp2f(s[0] * SC);
      const float p1 = exp2f(s[1] * SC);
      const float p2 = exp2f(s[2] * SC);
      const float p3 = exp2f(s[3] * SC);
      lacc += (p0 + p1) + (p2 + p3);
      intx2 pv;
      pv[0] = (int)pack2(p0, p1);
      pv[1] = (int)pack2(p2, p3);
      *(intx2*)(Pw + (w*16 + col) * PSTR + mh*16 + quad*4) = pv;
    }
  }
}

// BF=true:  mk = mkT [HW][CK] bf16, qk = qkT [HW][CK] bf16, mv = [CV][HW] bf16
// BF=false: original f32 layouts ([CK][HW], [CK][HW], [CV][HW])
// 512 threads (8 waves), 1 block/CU. Wave w: GEMM1 q-tile w; GEMM2 cv rows
// [w*64, +64) x all 128 q. Software-pipelined: GEMM1(it+1) interleaved with
// GEMM2(it); single barrier per iteration; P double-buffered.
template<bool BF>
__global__ __launch_bounds__(512, 2) void attn_main(
    const void* __restrict__ Mkp, const void* __restrict__ Qkp,
    const void* __restrict__ Mvp, float* __restrict__ Out)
{
  __shared__ alignas(16) short Pt[2][BQ * PSTR];   // 36864 B
  __shared__ float lsum[BQ];

  const int bx   = blockIdx.x;
  const int b    = bx & 7;            // XCD-affine: batch b -> XCD b
  const int q0   = (bx >> 3) * BQ;
  const int tid  = threadIdx.x;
  const int w    = tid >> 6;          // wave 0..7
  const int lane = tid & 63;
  const int quad = lane >> 4;
  const int col  = lane & 15;

  const size_t esz = BF ? 2 : 4;
  const char* mk = (const char*)Mkp + (size_t)b * CKD * HW * esz;
  const char* qk = (const char*)Qkp + (size_t)b * CKD * HW * esz;
  const char* mv = (const char*)Mvp + (size_t)b * CVD * HW * esz;
  float*      out = Out + (size_t)b * CVD * HW;

  if (tid < BQ) lsum[tid] = 0.0f;

  // B-fragments of qk (fixed for whole block): wave w owns q-tile w.
  short8 bq[2];
  #pragma unroll
  for (int ks = 0; ks < 2; ++ks) {
    if constexpr (BF)
      bq[ks] = ld8_contig<true>(qk, (size_t)(q0 + w*16 + col) * CKD + ks*32 + quad*8);
    else
      bq[ks] = ld8_strided<false>(qk, (ks*32 + quad*8) * HW + q0 + w*16 + col);
  }

  floatx4 acc[4][8];   // [ch][qh]: wave w owns cv rows [w*64, +64), all 128 q
  #pragma unroll
  for (int i = 0; i < 4; ++i)
    #pragma unroll
    for (int j = 0; j < 8; ++j) acc[i][j] = (floatx4)0.0f;

  float lacc = 0.0f;
  const float SC = 0.18033688011112042f;

  // ---- prologue: mv loads for it=0; GEMM1(0) -> Pt[0]
  short8 avA[4][2], avB[4][2];
  #pragma unroll
  for (int ch = 0; ch < 4; ++ch)
    #pragma unroll
    for (int ks = 0; ks < 2; ++ks)
      avA[ch][ks] = ld8_contig<BF>(mv, (size_t)(w*64 + ch*16 + col) * HW + ks*32 + quad*8);

  #pragma unroll
  for (int mh = 0; mh < 4; ++mh) {
    floatx4 s = (floatx4)0.0f;
    #pragma unroll
    for (int ks = 0; ks < 2; ++ks)
      s = MFMA16(ldA<BF>(mk, 0, mh, ks, quad, col), bq[ks], s);
    const float p0 = exp2f(s[0] * SC);
    const float p1 = exp2f(s[1] * SC);
    const float p2 = exp2f(s[2] * SC);
    const float p3 = exp2f(s[3] * SC);
    lacc += (p0 + p1) + (p2 + p3);
    intx2 pv;
    pv[0] = (int)pack2(p0, p1);
    pv[1] = (int)pack2(p2, p3);
    *(intx2*)(&Pt[0][0] + (w*16 + col) * PSTR + mh*16 + quad*4) = pv;
  }
  __syncthreads();

  // ---- main loop, 2 steps per trip (av ping-pong, P ping-pong)
  #pragma unroll 1
  for (int it2 = 0; it2 < NIT; it2 += 2) {
    attn_step<BF>(mk, mv, bq, acc, lacc, w, quad, col, it2,
                  avA, avB, &Pt[0][0], &Pt[1][0]);
    __syncthreads();
    attn_step<BF>(mk, mv, bq, acc, lacc, w, quad, col, it2 + 1,
                  avB, avA, &Pt[1][0], &Pt[0][0]);
    __syncthreads();
  }

  // ---- softmax denominators: 4 quads contribute per q column
  atomicAdd(&lsum[w*16 + col], lacc);
  __syncthreads();

  float rl[8];
  #pragma unroll
  for (int qh = 0; qh < 8; ++qh) rl[qh] = 1.0f / lsum[qh*16 + col];

  // ---- epilogue: normalize + store f32
  #pragma unroll
  for (int ch = 0; ch < 4; ++ch) {
    #pragma unroll
    for (int r = 0; r < 4; ++r) {
      const int cv = w*64 + ch*16 + quad*4 + r;
      float* orow = out + (size_t)cv * HW + q0 + col;
      #pragma unroll
      for (int qh = 0; qh < 8; ++qh)
        orow[qh*16] = acc[ch][qh][r] * rl[qh];
    }
  }
}

extern "C" void kernel_launch(void* const* d_in, const int* in_sizes, int n_in,
                              void* d_out, int out_size, void* d_ws, size_t ws_size,
                              hipStream_t stream) {
  const float* Mk = (const float*)d_in[0];
  const float* Qk = (const float*)d_in[1];
  const float* Mv = (const float*)d_in[2];
  float* Out = (float*)d_out;
  (void)in_sizes; (void)n_in; (void)out_size;

  const size_t NMK = (size_t)NBATCH * CKD * HW;   // 2,097,152
  const size_t NMV = (size_t)NBATCH * CVD * HW;   // 16,777,216
  const size_t need = (2 * NMK + NMV) * 2;        // 41,943,040 B

  if (ws_size >= need) {
    unsigned short* mkw = (unsigned short*)d_ws;
    unsigned short* qkw = mkw + NMK;
    unsigned short* mvw = qkw + NMK;
    const int mvBlocks = (int)(NMV / (256 * 8));  // 8 elems/thread
    prepass<<<256 + mvBlocks, 256, 0, stream>>>(Mk, Qk, Mv, mkw, qkw, mvw);
    attn_main<true><<<NBATCH * (HW/BQ), 512, 0, stream>>>(mkw, qkw, mvw, Out);
  } else {
    attn_main<false><<<NBATCH * (HW/BQ), 512, 0, stream>>>(Mk, Qk, Mv, Out);
  }
}